// Round 6
// baseline (21.842 us; speedup 1.0000x reference)
//
#include <hip/hip_runtime.h>

// LengthRegulator fused: B=16, T=512, D=384, DUR_MAX=8, MAX_OUT=3584
// out[b, j, :] = x[b, searchsorted_right(cumsum(dur[b]), j), :]  if j < total(b) else 0
//
// Round 6 (vs round-2 best @ 20.16us):
//  - ROWS_PB back to 32 (round-5's 64 was neutral/worse).
//  - searchsorted REPLACED by LDS scatter: after the scan each thread knows
//    frames 2t/2t+1's [start,end) output intervals; it writes srcs[] directly
//    for rows inside this block's window. Kills the 9-step dependent LDS
//    binary-search latency chain in every block's prologue (~0.45us ramp),
//    drops ends[512] LDS and one barrier.
//  - branchless copy: unconditional load from max(src,0) + mask multiply so
//    the 12 loads/thread pipeline without exec-mask control flow.

#define B_       16
#define T_       512
#define D_       384
#define MAX_OUT_ 3584            // T*(DUR_MAX-1)
#define ROW_F4   (D_ / 4)        // 96 float4 per row
#define ROWS_PB  32              // rows per block
#define BLK_PB   (MAX_OUT_ / ROWS_PB)        // 112 blocks per batch
#define F4_PB    (ROWS_PB * ROW_F4)          // 3072 float4 per block -> 12/thread

__global__ __launch_bounds__(256) void lr_fused_kernel(
    const float4* __restrict__ x4, const int* __restrict__ dur,
    float4* __restrict__ out4) {
  const int b  = blockIdx.y;
  const int r0 = blockIdx.x * ROWS_PB;     // first output row of this block
  const int t  = threadIdx.x;              // 0..255

  __shared__ int srcs[ROWS_PB];            // source frame per row (-1 = zero-fill)
  __shared__ int wsum[4];

  // ---- per-batch inclusive scan: 2 dur values per thread --------------------
  const int2 dd = ((const int2*)dur)[b * (T_ / 2) + t];  // dur[2t], dur[2t+1]
  const int lane = t & 63;
  const int wave = t >> 6;                 // 0..3
  int v = dd.x + dd.y;
  #pragma unroll
  for (int off = 1; off < 64; off <<= 1) {
    int n = __shfl_up(v, off, 64);
    if (lane >= off) v += n;
  }
  if (lane == 63) wsum[wave] = v;
  if (t < ROWS_PB) srcs[t] = -1;           // init before barrier; tail rows stay -1
  __syncthreads();
  int wpre = 0;
  #pragma unroll
  for (int w = 0; w < 3; ++w)
    if (w < wave) wpre += wsum[w];
  const int e1   = v + wpre;               // ends[2t+1] (inclusive cumsum)
  const int end0 = e1 - dd.y;              // ends[2t]
  const int st0  = end0 - dd.x;

  // ---- scatter inverse map for this block's 32-row window -------------------
  {
    const int lo0 = st0  > r0 ? st0  : r0;
    const int hi0 = end0 < r0 + ROWS_PB ? end0 : r0 + ROWS_PB;
    for (int k = lo0; k < hi0; ++k) srcs[k - r0] = 2 * t;
    const int lo1 = end0 > r0 ? end0 : r0;
    const int hi1 = e1   < r0 + ROWS_PB ? e1   : r0 + ROWS_PB;
    for (int k = lo1; k < hi1; ++k) srcs[k - r0] = 2 * t + 1;
  }
  __syncthreads();

  // ---- flat coalesced copy: 12 float4 per thread, branchless ----------------
  const float4* __restrict__ xb = x4 + (size_t)b * T_ * ROW_F4;
  float4* __restrict__ ob = out4 + ((size_t)b * MAX_OUT_ + r0) * ROW_F4;
  #pragma unroll
  for (int k = 0; k < F4_PB / 256; ++k) {
    const int idx = k * 256 + t;           // 0..3071
    const int rl  = idx / ROW_F4;          // local row 0..31
    const int col = idx - rl * ROW_F4;     // 0..95
    const int src = srcs[rl];
    const int srow = src > 0 ? src : 0;    // clamped, load always valid
    float4 val = xb[srow * ROW_F4 + col];
    const float m = src >= 0 ? 1.0f : 0.0f;
    val.x *= m; val.y *= m; val.z *= m; val.w *= m;
    ob[idx] = val;
  }
}

extern "C" void kernel_launch(void* const* d_in, const int* in_sizes, int n_in,
                              void* d_out, int out_size, void* d_ws, size_t ws_size,
                              hipStream_t stream) {
  const float* x   = (const float*)d_in[0];   // (B, T, D) fp32
  const int*   dur = (const int*)d_in[1];     // (B, T) int32
  float* out = (float*)d_out;                 // (B, MAX_OUT, D) fp32

  dim3 grid(BLK_PB, B_);                      // (112, 16)
  lr_fused_kernel<<<grid, 256, 0, stream>>>(
      (const float4*)x, dur, (float4*)out);
}

// Round 7
// 19.958 us; speedup vs baseline: 1.0944x; 1.0944x over previous
//
#include <hip/hip_runtime.h>

// LengthRegulator fused: B=16, T=512, D=384, DUR_MAX=8, MAX_OUT=3584
// out[b, j, :] = x[b, searchsorted_right(cumsum(dur[b]), j), :]  if j < total(b) else 0
//
// Round 7 = round-2 baseline (20.16us best) + ONE change: the 9-step dependent
// LDS binary search is replaced by a direct LDS scatter (each thread knows its
// two frames' [start,end) output intervals from the scan and writes srcs[]
// for rows inside this block's window). Guarded loads KEPT (round-6's
// branchless copy was the regression: ~50% of rows are zero-fill and the
// exec-mask branch skips their loads entirely).

#define B_       16
#define T_       512
#define D_       384
#define MAX_OUT_ 3584            // T*(DUR_MAX-1)
#define ROW_F4   (D_ / 4)        // 96 float4 per row
#define ROWS_PB  32              // rows per block
#define BLK_PB   (MAX_OUT_ / ROWS_PB)        // 112 blocks per batch
#define F4_PB    (ROWS_PB * ROW_F4)          // 3072 float4 per block -> 12/thread

__global__ __launch_bounds__(256) void lr_fused_kernel(
    const float4* __restrict__ x4, const int* __restrict__ dur,
    float4* __restrict__ out4) {
  const int b  = blockIdx.y;
  const int r0 = blockIdx.x * ROWS_PB;     // first output row of this block
  const int t  = threadIdx.x;              // 0..255

  __shared__ int srcs[ROWS_PB];            // source frame per row (-1 = zero-fill)
  __shared__ int wsum[4];

  // ---- per-batch inclusive scan: 2 dur values per thread --------------------
  const int2 dd = ((const int2*)dur)[b * (T_ / 2) + t];  // dur[2t], dur[2t+1]
  const int lane = t & 63;
  const int wave = t >> 6;                 // 0..3
  int v = dd.x + dd.y;
  #pragma unroll
  for (int off = 1; off < 64; off <<= 1) {
    int n = __shfl_up(v, off, 64);
    if (lane >= off) v += n;
  }
  if (lane == 63) wsum[wave] = v;
  if (t < ROWS_PB) srcs[t] = -1;           // tail rows stay -1 (zero-fill)
  __syncthreads();
  int wpre = 0;
  #pragma unroll
  for (int w = 0; w < 3; ++w)
    if (w < wave) wpre += wsum[w];
  const int e1   = v + wpre;               // ends[2t+1] (inclusive cumsum)
  const int end0 = e1 - dd.y;              // ends[2t]
  const int st0  = end0 - dd.x;

  // ---- scatter inverse map for this block's 32-row window -------------------
  {
    const int lo0 = st0  > r0 ? st0  : r0;
    const int hi0 = end0 < r0 + ROWS_PB ? end0 : r0 + ROWS_PB;
    for (int k = lo0; k < hi0; ++k) srcs[k - r0] = 2 * t;
    const int lo1 = end0 > r0 ? end0 : r0;
    const int hi1 = e1   < r0 + ROWS_PB ? e1   : r0 + ROWS_PB;
    for (int k = lo1; k < hi1; ++k) srcs[k - r0] = 2 * t + 1;
  }
  __syncthreads();

  // ---- flat coalesced copy: 12 float4 per thread, guarded loads -------------
  const float4* __restrict__ xb = x4 + (size_t)b * T_ * ROW_F4;
  float4* __restrict__ ob = out4 + ((size_t)b * MAX_OUT_ + r0) * ROW_F4;
  #pragma unroll
  for (int k = 0; k < F4_PB / 256; ++k) {
    const int idx = k * 256 + t;           // 0..3071
    const int rl  = idx / ROW_F4;          // local row 0..31
    const int col = idx - rl * ROW_F4;     // 0..95
    const int src = srcs[rl];
    float4 val = make_float4(0.f, 0.f, 0.f, 0.f);
    if (src >= 0) val = xb[src * ROW_F4 + col];
    ob[idx] = val;
  }
}

extern "C" void kernel_launch(void* const* d_in, const int* in_sizes, int n_in,
                              void* d_out, int out_size, void* d_ws, size_t ws_size,
                              hipStream_t stream) {
  const float* x   = (const float*)d_in[0];   // (B, T, D) fp32
  const int*   dur = (const int*)d_in[1];     // (B, T) int32
  float* out = (float*)d_out;                 // (B, MAX_OUT, D) fp32

  dim3 grid(BLK_PB, B_);                      // (112, 16)
  lr_fused_kernel<<<grid, 256, 0, stream>>>(
      (const float4*)x, dur, (float4*)out);
}